// Round 6
// baseline (987.763 us; speedup 1.0000x reference)
//
#include <hip/hip_runtime.h>

typedef unsigned short u16;
typedef unsigned int u32;
typedef __attribute__((ext_vector_type(8))) short bf16x8;
typedef __attribute__((ext_vector_type(8))) unsigned short u16x8;
typedef __attribute__((ext_vector_type(4))) unsigned short u16x4;
typedef __attribute__((ext_vector_type(4))) float f32x4;
typedef __attribute__((ext_vector_type(4))) unsigned int u32x4;

#define S_LEN 2048
#define NB 2
#define NH 32
#define NKVH 8
#define HD 128
#define DMODEL 4096
#define NEG_BIG (-1.0e30f)

__device__ __forceinline__ float bf2f(u16 x) {
  union { u32 u; float f; } v; v.u = ((u32)x) << 16; return v.f;
}
__device__ __forceinline__ u16 f2bf(float f) {
  union { float f; u32 u; } v; v.f = f;
  u32 r = v.u + 0x7FFFu + ((v.u >> 16) & 1u);
  return (u16)(r >> 16);
}

// Async global->LDS, 16B per lane. LDS dest must be wave-uniform base; HW
// writes base + lane*16.
__device__ __forceinline__ void gload16(const void* g, void* l) {
  __builtin_amdgcn_global_load_lds(
      (const __attribute__((address_space(1))) void*)g,
      (__attribute__((address_space(3))) void*)l, 16, 0, 0);
}

// ---------------------------------------------------------------------------
// x fp32 -> bf16 (16,777,216 elems), 8 elems/thread.
// ---------------------------------------------------------------------------
__global__ __launch_bounds__(256) void convert_x(const float* __restrict__ x,
                                                 u16* __restrict__ xb)
{
  int i = blockIdx.x * 256 + threadIdx.x;
  f32x4 a = *(const f32x4*)&x[(size_t)i * 8];
  f32x4 b = *(const f32x4*)&x[(size_t)i * 8 + 4];
  u16x8 h = { f2bf(a[0]), f2bf(a[1]), f2bf(a[2]), f2bf(a[3]),
              f2bf(b[0]), f2bf(b[1]), f2bf(b[2]), f2bf(b[3]) };
  *(u16x8*)&xb[(size_t)i * 8] = h;
}

// ---------------------------------------------------------------------------
// Transpose+convert: W fp32 (4096=K rows, N cols) -> out bf16 (N rows, 4096).
// ---------------------------------------------------------------------------
__global__ __launch_bounds__(256) void transpose_w(const float* __restrict__ W,
                                                   u16* __restrict__ out,
                                                   int N)
{
  __shared__ u16 Ls[64 * 68];
  const int t  = threadIdx.x;
  const int k0 = blockIdx.x * 64;
  const int n0 = blockIdx.y * 64;
#pragma unroll
  for (int i = 0; i < 4; ++i) {
    int kr = (t >> 4) + i * 16;
    int nc = (t & 15) * 4;
    f32x4 v = *(const f32x4*)&W[(size_t)(k0 + kr) * N + n0 + nc];
    u16x4 h = { f2bf(v[0]), f2bf(v[1]), f2bf(v[2]), f2bf(v[3]) };
    *(u16x4*)&Ls[kr * 68 + nc] = h;
  }
  __syncthreads();
#pragma unroll
  for (int i = 0; i < 2; ++i) {
    int nr = (t >> 3) + i * 32;
    int kc = (t & 7) * 8;
    u16x8 h;
#pragma unroll
    for (int j = 0; j < 8; ++j) h[j] = Ls[(kc + j) * 68 + nr];
    *(u16x8*)&out[(size_t)(n0 + nr) * 4096 + k0 + kc] = h;
  }
}

// ---------------------------------------------------------------------------
// Transpose V: Yv bf16 (b,s,kvh,d) -> Vt bf16 (b,kvh,d,s). 64x64 tiles.
// ---------------------------------------------------------------------------
__global__ __launch_bounds__(256) void transpose_v(const u16* __restrict__ Yv,
                                                   u16* __restrict__ Vt)
{
  __shared__ u16 Ls[64 * 68];
  const int t  = threadIdx.x;
  const int s0 = blockIdx.x * 64;
  const int d0 = blockIdx.y * 64;
  const int z  = blockIdx.z;            // b*8 + kvh
#pragma unroll
  for (int i = 0; i < 2; ++i) {
    int sr = (t >> 3) + i * 32;
    int dc = (t & 7) * 8;
    u16x8 v = *(const u16x8*)&Yv[((size_t)(z >> 3) * S_LEN + s0 + sr) * 1024 +
                                 (z & 7) * 128 + d0 + dc];
    u16x4 lo = { v[0], v[1], v[2], v[3] };
    u16x4 hi = { v[4], v[5], v[6], v[7] };
    *(u16x4*)&Ls[sr * 68 + dc]     = lo;
    *(u16x4*)&Ls[sr * 68 + dc + 4] = hi;
  }
  __syncthreads();
#pragma unroll
  for (int i = 0; i < 2; ++i) {
    int dr = (t >> 3) + i * 32;
    int sc = (t & 7) * 8;
    u16x8 h;
#pragma unroll
    for (int j = 0; j < 8; ++j) h[j] = Ls[(sc + j) * 68 + dr];
    *(u16x8*)&Vt[((size_t)z * 128 + d0 + dr) * S_LEN + s0 + sc] = h;
  }
}

// ---------------------------------------------------------------------------
// Pipelined GEMM core (T2+T4+T5): 256x128 tile, BK=64, 8 waves (4M x 2N,
// 64x64 per wave). 3 LDS buffers (A 32KB + B 16KB each = 144 KB total).
// Single raw s_barrier + counted vmcnt(6) per K-tile; stage tile t+2 into
// buf[(t+2)%3] (== buf[(t-1)%3], whose reads finished before this barrier).
// LDS XOR swizzle: colblock ^ (row&7), realized as pre-swizzled global
// source col (linear gload_lds dest) + XOR on ds_read col (rule #21).
// ---------------------------------------------------------------------------
__device__ __forceinline__ void stage256(const u16* __restrict__ Ag,
                                         const u16* __restrict__ Bg,
                                         u16* as, u16* bs,
                                         int bm, int bn, int kt, int tid)
{
  const int wave = tid >> 6;
  const int rsub = tid >> 3;                       // 0..63
  const int col  = kt + (((tid & 7) ^ (rsub & 7)) * 8);
#pragma unroll
  for (int c = 0; c < 4; ++c)
    gload16(&Ag[(size_t)(bm + c * 64 + rsub) * 4096 + col],
            &as[c * 4096 + wave * 512]);
#pragma unroll
  for (int c = 0; c < 2; ++c)
    gload16(&Bg[(size_t)(bn + c * 64 + rsub) * 4096 + col],
            &bs[c * 4096 + wave * 512]);
}

#define GEMM256_BODY(Ag, Bg)                                                   \
  __shared__ u16 As[3][16384];                                                 \
  __shared__ u16 Bs[3][8192];                                                  \
  const int tid  = threadIdx.x;                                                \
  const int lane = tid & 63;                                                   \
  const int lr   = lane & 15;                                                  \
  const int quad = lane >> 4;                                                  \
  const int wave = tid >> 6;                                                   \
  const int wm   = (wave >> 1) * 64;                                           \
  const int wn   = (wave & 1) * 64;                                            \
  const int nwg  = (int)gridDim.x;                                             \
  const int id   = (int)blockIdx.x;                                            \
  const int swz  = (id & 7) * (nwg >> 3) + (id >> 3);                          \
  const int by   = swz / NBX;                                                  \
  const int bx   = swz - by * NBX;                                             \
  const int bm   = by * 256;                                                   \
  const int bn0  = bx * 128;                                                   \
  const f32x4 zero = {0.f, 0.f, 0.f, 0.f};                                     \
  f32x4 acc[4][4];                                                             \
  _Pragma("unroll")                                                            \
  for (int i = 0; i < 4; ++i)                                                  \
    _Pragma("unroll")                                                          \
    for (int j = 0; j < 4; ++j) acc[i][j] = zero;                              \
  stage256(Ag, Bg, As[0], Bs[0], bm, bn0, 0,  tid);                            \
  stage256(Ag, Bg, As[1], Bs[1], bm, bn0, 64, tid);                            \
  for (int t = 0; t < 63; ++t) {                                               \
    asm volatile("s_waitcnt vmcnt(6)" ::: "memory");                           \
    __builtin_amdgcn_s_barrier();                                              \
    if (t + 2 < 64)                                                            \
      stage256(Ag, Bg, As[(t + 2) % 3], Bs[(t + 2) % 3], bm, bn0,              \
               (t + 2) * 64, tid);                                             \
    const u16* as = As[t % 3];                                                 \
    const u16* bs = Bs[t % 3];                                                 \
    _Pragma("unroll")                                                          \
    for (int kk = 0; kk < 2; ++kk) {                                           \
      bf16x8 af[4], bfr[4];                                                    \
      _Pragma("unroll")                                                        \
      for (int mt = 0; mt < 4; ++mt)                                           \
        af[mt] = *(const bf16x8*)&as[(wm + mt * 16 + lr) * 64 +                \
                                     (((kk * 4 + quad) ^ (lr & 7)) * 8)];      \
      _Pragma("unroll")                                                        \
      for (int nt = 0; nt < 4; ++nt)                                           \
        bfr[nt] = *(const bf16x8*)&bs[(wn + nt * 16 + lr) * 64 +               \
                                      (((kk * 4 + quad) ^ (lr & 7)) * 8)];     \
      __builtin_amdgcn_s_setprio(1);                                           \
      _Pragma("unroll")                                                        \
      for (int mt = 0; mt < 4; ++mt)                                           \
        _Pragma("unroll")                                                      \
        for (int nt = 0; nt < 4; ++nt)                                         \
          acc[mt][nt] = __builtin_amdgcn_mfma_f32_16x16x32_bf16(               \
              af[mt], bfr[nt], acc[mt][nt], 0, 0, 0);                          \
      __builtin_amdgcn_s_setprio(0);                                           \
    }                                                                          \
  }                                                                            \
  asm volatile("s_waitcnt vmcnt(0)" ::: "memory");                             \
  __builtin_amdgcn_s_barrier();                                                \
  {                                                                            \
    const u16* as = As[0]; /* 63 % 3 == 0 */                                   \
    const u16* bs = Bs[0];                                                     \
    _Pragma("unroll")                                                          \
    for (int kk = 0; kk < 2; ++kk) {                                           \
      bf16x8 af[4], bfr[4];                                                    \
      _Pragma("unroll")                                                        \
      for (int mt = 0; mt < 4; ++mt)                                           \
        af[mt] = *(const bf16x8*)&as[(wm + mt * 16 + lr) * 64 +                \
                                     (((kk * 4 + quad) ^ (lr & 7)) * 8)];      \
      _Pragma("unroll")                                                        \
      for (int nt = 0; nt < 4; ++nt)                                           \
        bfr[nt] = *(const bf16x8*)&bs[(wn + nt * 16 + lr) * 64 +               \
                                      (((kk * 4 + quad) ^ (lr & 7)) * 8)];     \
      __builtin_amdgcn_s_setprio(1);                                           \
      _Pragma("unroll")                                                        \
      for (int mt = 0; mt < 4; ++mt)                                           \
        _Pragma("unroll")                                                      \
        for (int nt = 0; nt < 4; ++nt)                                         \
          acc[mt][nt] = __builtin_amdgcn_mfma_f32_16x16x32_bf16(               \
              af[mt], bfr[nt], acc[mt][nt], 0, 0, 0);                          \
      __builtin_amdgcn_s_setprio(0);                                           \
    }                                                                          \
  }

// QKV GEMM: A = xb bf16 (4096,4096); Bt bf16 (6144,4096). NBX = 6144/128 = 48.
__global__ __launch_bounds__(512) void gemm_qkv(const u16* __restrict__ A,
                                                const u16* __restrict__ Bt,
                                                u16* __restrict__ Yq,
                                                u16* __restrict__ Yk,
                                                u16* __restrict__ Yv)
{
  const int NBX = 48;
  GEMM256_BODY(A, Bt)
  u16* dst; size_t ldc; int nbase;
  if (bn0 < 4096)      { dst = Yq; ldc = 4096; nbase = bn0; }
  else if (bn0 < 5120) { dst = Yk; ldc = 1024; nbase = bn0 - 4096; }
  else                 { dst = Yv; ldc = 1024; nbase = bn0 - 5120; }
#pragma unroll
  for (int mt = 0; mt < 4; ++mt)
#pragma unroll
    for (int nt = 0; nt < 4; ++nt)
#pragma unroll
      for (int r = 0; r < 4; ++r) {
        size_t m = (size_t)(bm + wm + mt * 16 + quad * 4 + r);
        size_t n = (size_t)(nbase + wn + nt * 16 + lr);
        dst[m * ldc + n] = f2bf(acc[mt][nt][r]);
      }
}

// O GEMM: A = att bf16 (4096,4096); Bt = WoT bf16 (4096,4096); C fp32.
// NBX = 4096/128 = 32.
__global__ __launch_bounds__(512) void gemm_o(const u16* __restrict__ A,
                                              const u16* __restrict__ Bt,
                                              float* __restrict__ C)
{
  const int NBX = 32;
  GEMM256_BODY(A, Bt)
#pragma unroll
  for (int mt = 0; mt < 4; ++mt)
#pragma unroll
    for (int nt = 0; nt < 4; ++nt)
#pragma unroll
      for (int r = 0; r < 4; ++r) {
        size_t m = (size_t)(bm + wm + mt * 16 + quad * 4 + r);
        size_t n = (size_t)(bn0 + wn + nt * 16 + lr);
        C[m * 4096 + n] = acc[mt][nt][r];
      }
}

// ---------------------------------------------------------------------------
// RoPE in-place on Y[(b,s,nh,HD)] bf16; vectorized: 4 pairs (8 elems)/thread.
// ---------------------------------------------------------------------------
__global__ __launch_bounds__(256) void rope_v(u16* __restrict__ Y,
                                              const float* __restrict__ cp,
                                              const float* __restrict__ sp,
                                              int log2nh, int total)
{
  int g = blockIdx.x * 256 + threadIdx.x;
  if (g >= total) return;
  int j = (g & 15) * 4;
  int s = (g >> (4 + log2nh)) & (S_LEN - 1);
  u16x8 t = *(const u16x8*)&Y[(size_t)g * 8];
  f32x4 c  = *(const f32x4*)&cp[s * 64 + j];
  f32x4 sn = *(const f32x4*)&sp[s * 64 + j];
  u16x8 o;
#pragma unroll
  for (int p = 0; p < 4; ++p) {
    float tr = bf2f(t[2 * p]);
    float ti = bf2f(t[2 * p + 1]);
    o[2 * p]     = f2bf(tr * c[p] - ti * sn[p]);
    o[2 * p + 1] = f2bf(tr * sn[p] + ti * c[p]);
  }
  *(u16x8*)&Y[(size_t)g * 8] = o;
}

// ---------------------------------------------------------------------------
// Flash attention (unchanged from round 5). Block = 128 q-rows of one (b,h):
// 8 waves x 16 q-rows, 512 threads. KV tile = 64. Online softmax with the
// denominator computed by the PV MFMA via the ones-column (d=128 row of Vs).
// ---------------------------------------------------------------------------
__global__ __launch_bounds__(512) void attn_kernel(const u16* Q,
                                                   const u16* __restrict__ K,
                                                   const u16* __restrict__ V,
                                                   u16* O)
{
  __shared__ u16 Ks[64 * 136];     // (kv, d)
  __shared__ u16 Vs[144 * 72];     // (d, kv^swz); rows 128..143 = ones/zeros
  __shared__ u16 Ps[8 * 16 * 72];  // per-wave (q, kv^swz)

  const int tid  = threadIdx.x;
  const int wave = tid >> 6;
  const int lane = tid & 63;
  const int lr   = lane & 15;
  const int quad = lane >> 4;

  const int b   = blockIdx.z;
  const int h   = blockIdx.y;
  const int q0  = ((int)gridDim.x - 1 - (int)blockIdx.x) * 128;  // heavy first
  const int kvh = h >> 2;   // REP = 4

  // ones-column region init (written once; covered by in-loop barrier)
  for (int i = tid; i < 16 * 72; i += 512) {
    int dd = i / 72;
    Vs[(size_t)(128 + dd) * 72 + (i % 72)] = (dd == 0) ? (u16)0x3F80 : (u16)0;
  }

  const int wbase = q0 + wave * 16;
  const u16* qptr = Q + ((size_t)((b * S_LEN + wbase + lr) * NH + h)) * HD;
  bf16x8 aq[4];
#pragma unroll
  for (int c = 0; c < 4; ++c) aq[c] = *(const bf16x8*)(qptr + c * 32 + quad * 8);

  const f32x4 zero = {0.f, 0.f, 0.f, 0.f};
  f32x4 accO[9];
#pragma unroll
  for (int nt = 0; nt < 9; ++nt) accO[nt] = zero;
  float m_run[4];
#pragma unroll
  for (int r = 0; r < 4; ++r) m_run[r] = NEG_BIG;

  const float scale = 0.08838834764831845f;  // 1/sqrt(128)
  const int myq = wbase + quad * 4;

  // per-lane staging coords (constant across tiles); 512 threads, 2 chunks
  int krow_[2], d0_[2], vd_[2], vk8_[2];
  size_t kbase[2], vbase[2];
#pragma unroll
  for (int i = 0; i < 2; ++i) {
    int e = (tid + i * 512) * 8;
    krow_[i] = e >> 7;
    d0_[i]   = e & 127;
    int cch = tid + i * 512;
    vd_[i]  = cch >> 3;
    vk8_[i] = cch & 7;
    kbase[i] = ((size_t)((b * S_LEN + krow_[i]) * NKVH + kvh)) * HD + d0_[i];
    vbase[i] = ((size_t)((b * NKVH + kvh) * HD + vd_[i])) * S_LEN + vk8_[i] * 8;
  }

  // prologue: prefetch tile 0 into registers
  u32x4 kreg[2], vreg[2];
#pragma unroll
  for (int i = 0; i < 2; ++i) {
    kreg[i] = *(const u32x4*)&K[kbase[i]];
    vreg[i] = *(const u32x4*)&V[vbase[i]];
  }

  const int kv_end = q0 + 64;             // last tile covers rows q0..q0+127
  for (int kv0 = 0; kv0 <= kv_end; kv0 += 64) {
    const bool dg = (kv0 + 63 > wbase);   // wave-uniform mask flag
    __syncthreads();   // prev compute done reading LDS
    // write prefetched regs -> LDS: all vector b128, conflict-balanced
#pragma unroll
    for (int i = 0; i < 2; ++i) {
      *(u32x4*)&Ks[krow_[i] * 136 + d0_[i]] = kreg[i];
      *(u32x4*)&Vs[vd_[i] * 72 + ((vk8_[i] * 8) ^ (((vd_[i] >> 3) & 7) << 3))] = vreg[i];
    }
    __syncthreads();

    // issue prefetch for next tile; flies during compute below
    if (kv0 + 64 <= kv_end) {
#pragma unroll
      for (int i = 0; i < 2; ++i) {
        kreg[i] = *(const u32x4*)&K[kbase[i] + (size_t)(kv0 + 64) * (NKVH * HD)];
        vreg[i] = *(const u32x4*)&V[vbase[i] + kv0 + 64];
      }
    }

    // S = Q K^T : 16 q x 64 kv per wave (4 col-tiles)
    f32x4 sa[4];
    __builtin_amdgcn_s_setprio(1);
#pragma unroll
    for (int t = 0; t < 4; ++t) {
      f32x4 a = zero;
#pragma unroll
      for (int c = 0; c < 4; ++c) {
        bf16x8 bk = *(const bf16x8*)&Ks[(t * 16 + lr) * 136 + c * 32 + quad * 8];
        a = __builtin_amdgcn_mfma_f32_16x16x32_bf16(aq[c], bk, a, 0, 0, 0);
      }
      sa[t] = a;
    }
    __builtin_amdgcn_s_setprio(0);

    // online softmax per row (rows = myq + r); sum comes from the PV MFMA
    float alpha[4];
#pragma unroll
    for (int r = 0; r < 4; ++r) {
      const int row = myq + r;
      float s[4];
#pragma unroll
      for (int t = 0; t < 4; ++t) {
        float v = sa[t][r] * scale;
        if (dg) v = (kv0 + t * 16 + lr <= row) ? v : NEG_BIG;
        s[t] = v;
      }
      float mx = fmaxf(fmaxf(s[0], s[1]), fmaxf(s[2], s[3]));
#pragma unroll
      for (int off = 8; off >= 1; off >>= 1) mx = fmaxf(mx, __shfl_xor(mx, off));
      float mn = fmaxf(m_run[r], mx);
      alpha[r] = __expf(m_run[r] - mn);
      m_run[r] = mn;
      const int q  = quad * 4 + r;
      const int sw = (q & 7) << 3;
      const int base = wave * 1152 + q * 72;
#pragma unroll
      for (int t = 0; t < 4; ++t)
        Ps[base + ((t * 16 + lr) ^ sw)] = f2bf(__expf(s[t] - mn));
    }
#pragma unroll
    for (int nt = 0; nt < 9; ++nt)
#pragma unroll
      for (int r = 0; r < 4; ++r) accO[nt][r] *= alpha[r];

    // O += P V : 2 k-steps of 32 kv, 9 d-tiles (tile 8 = denominator)
    __builtin_amdgcn_s_setprio(1);
#pragma unroll
    for (int kt2 = 0; kt2 < 2; ++kt2) {
      bf16x8 pf = *(const bf16x8*)&Ps[wave * 1152 + lr * 72 +
                                      ((kt2 * 32 + quad * 8) ^ ((lr & 7) << 3))];
#pragma unroll
      for (int nt = 0; nt < 9; ++nt) {
        const int d = nt * 16 + lr;
        bf16x8 vf = *(const bf16x8*)&Vs[d * 72 +
                                        ((kt2 * 32 + quad * 8) ^ (((d >> 3) & 7) << 3))];
        accO[nt] = __builtin_amdgcn_mfma_f32_16x16x32_bf16(pf, vf, accO[nt], 0, 0, 0);
      }
    }
    __builtin_amdgcn_s_setprio(0);
  }

  // l for row q lives in lane lr==0 of the same quad (d=128 column)
  float rl[4];
#pragma unroll
  for (int r = 0; r < 4; ++r) {
    float l = __shfl(accO[8][r], lane & 48);
    rl[r] = 1.0f / l;
  }
#pragma unroll
  for (int nt = 0; nt < 8; ++nt)
#pragma unroll
    for (int r = 0; r < 4; ++r) {
      size_t q = (size_t)(wbase + quad * 4 + r);
      O[((size_t)b * S_LEN + q) * DMODEL + (size_t)h * HD + nt * 16 + lr] =
          f2bf(accO[nt][r] * rl[r]);
    }
}

extern "C" void kernel_launch(void* const* d_in, const int* in_sizes, int n_in,
                              void* d_out, int out_size, void* d_ws, size_t ws_size,
                              hipStream_t stream)
{
  const float* x  = (const float*)d_in[0];
  const float* cp = (const float*)d_in[1];
  const float* sp = (const float*)d_in[2];
  const float* Wq = (const float*)d_in[3];
  const float* Wk = (const float*)d_in[4];
  const float* Wv = (const float*)d_in[5];
  const float* Wo = (const float*)d_in[6];

  // ws layout (bf16 elems): Wt 25,165,824 | Yq 16,777,216 | Yk 4,194,304 |
  // Yv 4,194,304. Vt (4M elems) reuses the START of Wt (weights dead after
  // gemm_qkv; attn finishes before transpose_w(Wo) overwrites Wt).
  // xb (bf16 copy of x) lives in d_out — dead before gemm_o writes output.
  u16* Wt  = (u16*)d_ws;
  u16* Yq  = Wt + (size_t)25165824;
  u16* Yk  = Yq + (size_t)16777216;
  u16* Yv  = Yk + (size_t)4194304;
  u16* att = Yq;                       // attn output aliases Q
  u16* WoT = Wt;                       // dead after QKV GEMM
  u16* Vt  = Wt;                       // transposed V, dead before WoT write
  u16* xb  = (u16*)d_out;              // scratch in output buffer

  transpose_w<<<dim3(64, 64), 256, 0, stream>>>(Wq, Wt,                    4096);
  transpose_w<<<dim3(64, 16), 256, 0, stream>>>(Wk, Wt + (size_t)4096*4096, 1024);
  transpose_w<<<dim3(64, 16), 256, 0, stream>>>(Wv, Wt + (size_t)5120*4096, 1024);
  convert_x<<<8192, 256, 0, stream>>>(x, xb);
  gemm_qkv<<<768, 512, 0, stream>>>(xb, Wt, Yq, Yk, Yv);
  rope_v<<<8192, 256, 0, stream>>>(Yq, cp, sp, 5, 2097152);
  rope_v<<<2048, 256, 0, stream>>>(Yk, cp, sp, 3, 524288);
  transpose_v<<<dim3(32, 2, 16), 256, 0, stream>>>(Yv, Vt);
  attn_kernel<<<dim3(16, 32, 2), 512, 0, stream>>>(Yq, Yk, Vt, att);
  transpose_w<<<dim3(64, 64), 256, 0, stream>>>(Wo, WoT, 4096);
  gemm_o<<<512, 512, 0, stream>>>(att, WoT, (float*)d_out);
}

// Round 7
// 927.141 us; speedup vs baseline: 1.0654x; 1.0654x over previous
//
#include <hip/hip_runtime.h>

typedef unsigned short u16;
typedef unsigned int u32;
typedef __attribute__((ext_vector_type(8))) short bf16x8;
typedef __attribute__((ext_vector_type(8))) unsigned short u16x8;
typedef __attribute__((ext_vector_type(4))) unsigned short u16x4;
typedef __attribute__((ext_vector_type(4))) float f32x4;
typedef __attribute__((ext_vector_type(4))) unsigned int u32x4;

#define S_LEN 2048
#define NB 2
#define NH 32
#define NKVH 8
#define HD 128
#define DMODEL 4096
#define NEG_BIG (-1.0e30f)

__device__ __forceinline__ float bf2f(u16 x) {
  union { u32 u; float f; } v; v.u = ((u32)x) << 16; return v.f;
}
__device__ __forceinline__ u16 f2bf(float f) {
  union { float f; u32 u; } v; v.f = f;
  u32 r = v.u + 0x7FFFu + ((v.u >> 16) & 1u);
  return (u16)(r >> 16);
}

// Async global->LDS, 16B per lane. LDS dest must be wave-uniform base; HW
// writes base + lane*16.
__device__ __forceinline__ void gload16(const void* g, void* l) {
  __builtin_amdgcn_global_load_lds(
      (const __attribute__((address_space(1))) void*)g,
      (__attribute__((address_space(3))) void*)l, 16, 0, 0);
}

// ---------------------------------------------------------------------------
// x fp32 -> bf16 (16,777,216 elems), 8 elems/thread.
// ---------------------------------------------------------------------------
__global__ __launch_bounds__(256) void convert_x(const float* __restrict__ x,
                                                 u16* __restrict__ xb)
{
  int i = blockIdx.x * 256 + threadIdx.x;
  f32x4 a = *(const f32x4*)&x[(size_t)i * 8];
  f32x4 b = *(const f32x4*)&x[(size_t)i * 8 + 4];
  u16x8 h = { f2bf(a[0]), f2bf(a[1]), f2bf(a[2]), f2bf(a[3]),
              f2bf(b[0]), f2bf(b[1]), f2bf(b[2]), f2bf(b[3]) };
  *(u16x8*)&xb[(size_t)i * 8] = h;
}

// ---------------------------------------------------------------------------
// Transpose+convert: W fp32 (4096=K rows, N cols) -> out bf16 (N rows, 4096).
// ---------------------------------------------------------------------------
__global__ __launch_bounds__(256) void transpose_w(const float* __restrict__ W,
                                                   u16* __restrict__ out,
                                                   int N)
{
  __shared__ u16 Ls[64 * 68];
  const int t  = threadIdx.x;
  const int k0 = blockIdx.x * 64;
  const int n0 = blockIdx.y * 64;
#pragma unroll
  for (int i = 0; i < 4; ++i) {
    int kr = (t >> 4) + i * 16;
    int nc = (t & 15) * 4;
    f32x4 v = *(const f32x4*)&W[(size_t)(k0 + kr) * N + n0 + nc];
    u16x4 h = { f2bf(v[0]), f2bf(v[1]), f2bf(v[2]), f2bf(v[3]) };
    *(u16x4*)&Ls[kr * 68 + nc] = h;
  }
  __syncthreads();
#pragma unroll
  for (int i = 0; i < 2; ++i) {
    int nr = (t >> 3) + i * 32;
    int kc = (t & 7) * 8;
    u16x8 h;
#pragma unroll
    for (int j = 0; j < 8; ++j) h[j] = Ls[(kc + j) * 68 + nr];
    *(u16x8*)&out[(size_t)(n0 + nr) * 4096 + k0 + kc] = h;
  }
}

// ---------------------------------------------------------------------------
// Transpose V: Yv bf16 (b,s,kvh,d) -> Vt bf16 (b,kvh,d,s). 64x64 tiles.
// ---------------------------------------------------------------------------
__global__ __launch_bounds__(256) void transpose_v(const u16* __restrict__ Yv,
                                                   u16* __restrict__ Vt)
{
  __shared__ u16 Ls[64 * 68];
  const int t  = threadIdx.x;
  const int s0 = blockIdx.x * 64;
  const int d0 = blockIdx.y * 64;
  const int z  = blockIdx.z;            // b*8 + kvh
#pragma unroll
  for (int i = 0; i < 2; ++i) {
    int sr = (t >> 3) + i * 32;
    int dc = (t & 7) * 8;
    u16x8 v = *(const u16x8*)&Yv[((size_t)(z >> 3) * S_LEN + s0 + sr) * 1024 +
                                 (z & 7) * 128 + d0 + dc];
    u16x4 lo = { v[0], v[1], v[2], v[3] };
    u16x4 hi = { v[4], v[5], v[6], v[7] };
    *(u16x4*)&Ls[sr * 68 + dc]     = lo;
    *(u16x4*)&Ls[sr * 68 + dc + 4] = hi;
  }
  __syncthreads();
#pragma unroll
  for (int i = 0; i < 2; ++i) {
    int dr = (t >> 3) + i * 32;
    int sc = (t & 7) * 8;
    u16x8 h;
#pragma unroll
    for (int j = 0; j < 8; ++j) h[j] = Ls[(sc + j) * 68 + dr];
    *(u16x8*)&Vt[((size_t)z * 128 + d0 + dr) * S_LEN + s0 + sc] = h;
  }
}

// ---------------------------------------------------------------------------
// QKV GEMM (round-5 proven structure: 128x128, BK=64, T2 XOR swizzle, 256 thr)
// + FUSED RoPE in the epilogue for Q/K blocks (bn < 5120): lanes hold the
// (even,odd) head-dim pair in adjacent lanes; one shfl_xor(1) exchanges the
// partner, out = val*c +/- other*sn, applied on fp32 acc BEFORE bf16 store.
// ---------------------------------------------------------------------------
__global__ __launch_bounds__(256) void gemm_qkv(const u16* __restrict__ A,
                                                const u16* __restrict__ Bt,
                                                const float* __restrict__ cp,
                                                const float* __restrict__ sp,
                                                u16* __restrict__ Yq,
                                                u16* __restrict__ Yk,
                                                u16* __restrict__ Yv)
{
  __shared__ u16 As[128 * 64];
  __shared__ u16 Bs[128 * 64];
  const int tid  = threadIdx.x;
  const int wave = tid >> 6;
  const int lane = tid & 63;
  const int lr   = lane & 15;
  const int quad = lane >> 4;
  const int wm   = (wave >> 1) * 64;
  const int wn   = (wave & 1) * 64;
  const int bm   = blockIdx.y * 128;
  const int bn   = blockIdx.x * 128;

  // staging: per wave 4 chunks of 8 rows; source col pre-swizzled so data
  // lands at LDS colblock ^ (row&7)  (row&7 == lane>>3 here)
  const int col = (((lane & 7) ^ (lane >> 3)) * 8);
  const int r0  = wave * 32 + (lane >> 3);   // + c*8

  const f32x4 zero = {0.f, 0.f, 0.f, 0.f};
  f32x4 acc[4][4];
#pragma unroll
  for (int i = 0; i < 4; ++i)
#pragma unroll
    for (int j = 0; j < 4; ++j) acc[i][j] = zero;

  for (int kt = 0; kt < 4096; kt += 64) {
    __syncthreads();
#pragma unroll
    for (int c = 0; c < 4; ++c) {
      gload16(&A [(size_t)(bm + r0 + c * 8) * 4096 + kt + col],
              &As[wave * 2048 + c * 512]);
      gload16(&Bt[(size_t)(bn + r0 + c * 8) * 4096 + kt + col],
              &Bs[wave * 2048 + c * 512]);
    }
    __syncthreads();

#pragma unroll
    for (int kk = 0; kk < 2; ++kk) {
      bf16x8 af[4], bfr[4];
#pragma unroll
      for (int mt = 0; mt < 4; ++mt)
        af[mt] = *(const bf16x8*)&As[(wm + mt * 16 + lr) * 64 +
                                     (((kk * 4 + quad) ^ (lr & 7)) * 8)];
#pragma unroll
      for (int nt = 0; nt < 4; ++nt)
        bfr[nt] = *(const bf16x8*)&Bs[(wn + nt * 16 + lr) * 64 +
                                      (((kk * 4 + quad) ^ (lr & 7)) * 8)];
#pragma unroll
      for (int mt = 0; mt < 4; ++mt)
#pragma unroll
        for (int nt = 0; nt < 4; ++nt)
          acc[mt][nt] = __builtin_amdgcn_mfma_f32_16x16x32_bf16(af[mt], bfr[nt], acc[mt][nt], 0, 0, 0);
    }
  }

  u16* dst; size_t ldc; int nbase; bool dorope;
  if (bn < 4096)      { dst = Yq; ldc = 4096; nbase = bn;        dorope = true;  }
  else if (bn < 5120) { dst = Yk; ldc = 1024; nbase = bn - 4096; dorope = true;  }
  else                { dst = Yv; ldc = 1024; nbase = bn - 5120; dorope = false; }

  if (dorope) {
    const float sgn = (lane & 1) ? 1.f : -1.f;
#pragma unroll
    for (int nt = 0; nt < 4; ++nt) {
      const int n = nbase + wn + nt * 16 + lr;
      const int j = (n & 127) >> 1;
#pragma unroll
      for (int mt = 0; mt < 4; ++mt)
#pragma unroll
        for (int r = 0; r < 4; ++r) {
          const int m = bm + wm + mt * 16 + quad * 4 + r;
          const int s = m & (S_LEN - 1);
          float val = acc[mt][nt][r];
          float oth = __shfl_xor(val, 1);
          float c   = cp[s * 64 + j];
          float sn  = sp[s * 64 + j];
          dst[(size_t)m * ldc + n] = f2bf(val * c + sgn * oth * sn);
        }
    }
  } else {
#pragma unroll
    for (int mt = 0; mt < 4; ++mt)
#pragma unroll
      for (int nt = 0; nt < 4; ++nt)
#pragma unroll
        for (int r = 0; r < 4; ++r) {
          size_t m = (size_t)(bm + wm + mt * 16 + quad * 4 + r);
          size_t n = (size_t)(nbase + wn + nt * 16 + lr);
          dst[m * ldc + n] = f2bf(acc[mt][nt][r]);
        }
  }
}

// ---------------------------------------------------------------------------
// O GEMM (round-5 proven structure): A = att bf16 (4096, 4096); Bt = WoT
// bf16 (4096, 4096); C fp32 out.
// ---------------------------------------------------------------------------
__global__ __launch_bounds__(256) void gemm_o(const u16* __restrict__ A,
                                              const u16* __restrict__ Bt,
                                              float* __restrict__ C)
{
  __shared__ u16 As[128 * 64];
  __shared__ u16 Bs[128 * 64];
  const int tid  = threadIdx.x;
  const int wave = tid >> 6;
  const int lane = tid & 63;
  const int lr   = lane & 15;
  const int quad = lane >> 4;
  const int wm   = (wave >> 1) * 64;
  const int wn   = (wave & 1) * 64;
  const int bm   = blockIdx.y * 128;
  const int bn   = blockIdx.x * 128;

  const int col = (((lane & 7) ^ (lane >> 3)) * 8);
  const int r0  = wave * 32 + (lane >> 3);

  const f32x4 zero = {0.f, 0.f, 0.f, 0.f};
  f32x4 acc[4][4];
#pragma unroll
  for (int i = 0; i < 4; ++i)
#pragma unroll
    for (int j = 0; j < 4; ++j) acc[i][j] = zero;

  for (int kt = 0; kt < 4096; kt += 64) {
    __syncthreads();
#pragma unroll
    for (int c = 0; c < 4; ++c) {
      gload16(&A [(size_t)(bm + r0 + c * 8) * 4096 + kt + col],
              &As[wave * 2048 + c * 512]);
      gload16(&Bt[(size_t)(bn + r0 + c * 8) * 4096 + kt + col],
              &Bs[wave * 2048 + c * 512]);
    }
    __syncthreads();

#pragma unroll
    for (int kk = 0; kk < 2; ++kk) {
      bf16x8 af[4], bfr[4];
#pragma unroll
      for (int mt = 0; mt < 4; ++mt)
        af[mt] = *(const bf16x8*)&As[(wm + mt * 16 + lr) * 64 +
                                     (((kk * 4 + quad) ^ (lr & 7)) * 8)];
#pragma unroll
      for (int nt = 0; nt < 4; ++nt)
        bfr[nt] = *(const bf16x8*)&Bs[(wn + nt * 16 + lr) * 64 +
                                      (((kk * 4 + quad) ^ (lr & 7)) * 8)];
#pragma unroll
      for (int mt = 0; mt < 4; ++mt)
#pragma unroll
        for (int nt = 0; nt < 4; ++nt)
          acc[mt][nt] = __builtin_amdgcn_mfma_f32_16x16x32_bf16(af[mt], bfr[nt], acc[mt][nt], 0, 0, 0);
    }
  }

#pragma unroll
  for (int mt = 0; mt < 4; ++mt)
#pragma unroll
    for (int nt = 0; nt < 4; ++nt)
#pragma unroll
      for (int r = 0; r < 4; ++r) {
        size_t m = (size_t)(bm + wm + mt * 16 + quad * 4 + r);
        size_t n = (size_t)(bn + wn + nt * 16 + lr);
        C[m * 4096 + n] = acc[mt][nt][r];
      }
}

// ---------------------------------------------------------------------------
// Flash attention (unchanged from round 5). Block = 128 q-rows of one (b,h):
// 8 waves x 16 q-rows, 512 threads. KV tile = 64. Online softmax with the
// denominator computed by the PV MFMA via the ones-column (d=128 row of Vs).
// ---------------------------------------------------------------------------
__global__ __launch_bounds__(512) void attn_kernel(const u16* Q,
                                                   const u16* __restrict__ K,
                                                   const u16* __restrict__ V,
                                                   u16* O)
{
  __shared__ u16 Ks[64 * 136];     // (kv, d)
  __shared__ u16 Vs[144 * 72];     // (d, kv^swz); rows 128..143 = ones/zeros
  __shared__ u16 Ps[8 * 16 * 72];  // per-wave (q, kv^swz)

  const int tid  = threadIdx.x;
  const int wave = tid >> 6;
  const int lane = tid & 63;
  const int lr   = lane & 15;
  const int quad = lane >> 4;

  const int b   = blockIdx.z;
  const int h   = blockIdx.y;
  const int q0  = ((int)gridDim.x - 1 - (int)blockIdx.x) * 128;  // heavy first
  const int kvh = h >> 2;   // REP = 4

  // ones-column region init (written once; covered by in-loop barrier)
  for (int i = tid; i < 16 * 72; i += 512) {
    int dd = i / 72;
    Vs[(size_t)(128 + dd) * 72 + (i % 72)] = (dd == 0) ? (u16)0x3F80 : (u16)0;
  }

  const int wbase = q0 + wave * 16;
  const u16* qptr = Q + ((size_t)((b * S_LEN + wbase + lr) * NH + h)) * HD;
  bf16x8 aq[4];
#pragma unroll
  for (int c = 0; c < 4; ++c) aq[c] = *(const bf16x8*)(qptr + c * 32 + quad * 8);

  const f32x4 zero = {0.f, 0.f, 0.f, 0.f};
  f32x4 accO[9];
#pragma unroll
  for (int nt = 0; nt < 9; ++nt) accO[nt] = zero;
  float m_run[4];
#pragma unroll
  for (int r = 0; r < 4; ++r) m_run[r] = NEG_BIG;

  const float scale = 0.08838834764831845f;  // 1/sqrt(128)
  const int myq = wbase + quad * 4;

  // per-lane staging coords (constant across tiles); 512 threads, 2 chunks
  int krow_[2], d0_[2], vd_[2], vk8_[2];
  size_t kbase[2], vbase[2];
#pragma unroll
  for (int i = 0; i < 2; ++i) {
    int e = (tid + i * 512) * 8;
    krow_[i] = e >> 7;
    d0_[i]   = e & 127;
    int cch = tid + i * 512;
    vd_[i]  = cch >> 3;
    vk8_[i] = cch & 7;
    kbase[i] = ((size_t)((b * S_LEN + krow_[i]) * NKVH + kvh)) * HD + d0_[i];
    vbase[i] = ((size_t)((b * NKVH + kvh) * HD + vd_[i])) * S_LEN + vk8_[i] * 8;
  }

  // prologue: prefetch tile 0 into registers
  u32x4 kreg[2], vreg[2];
#pragma unroll
  for (int i = 0; i < 2; ++i) {
    kreg[i] = *(const u32x4*)&K[kbase[i]];
    vreg[i] = *(const u32x4*)&V[vbase[i]];
  }

  const int kv_end = q0 + 64;             // last tile covers rows q0..q0+127
  for (int kv0 = 0; kv0 <= kv_end; kv0 += 64) {
    const bool dg = (kv0 + 63 > wbase);   // wave-uniform mask flag
    __syncthreads();   // prev compute done reading LDS
    // write prefetched regs -> LDS: all vector b128, conflict-balanced
#pragma unroll
    for (int i = 0; i < 2; ++i) {
      *(u32x4*)&Ks[krow_[i] * 136 + d0_[i]] = kreg[i];
      *(u32x4*)&Vs[vd_[i] * 72 + ((vk8_[i] * 8) ^ (((vd_[i] >> 3) & 7) << 3))] = vreg[i];
    }
    __syncthreads();

    // issue prefetch for next tile; flies during compute below
    if (kv0 + 64 <= kv_end) {
#pragma unroll
      for (int i = 0; i < 2; ++i) {
        kreg[i] = *(const u32x4*)&K[kbase[i] + (size_t)(kv0 + 64) * (NKVH * HD)];
        vreg[i] = *(const u32x4*)&V[vbase[i] + kv0 + 64];
      }
    }

    // S = Q K^T : 16 q x 64 kv per wave (4 col-tiles)
    f32x4 sa[4];
    __builtin_amdgcn_s_setprio(1);
#pragma unroll
    for (int t = 0; t < 4; ++t) {
      f32x4 a = zero;
#pragma unroll
      for (int c = 0; c < 4; ++c) {
        bf16x8 bk = *(const bf16x8*)&Ks[(t * 16 + lr) * 136 + c * 32 + quad * 8];
        a = __builtin_amdgcn_mfma_f32_16x16x32_bf16(aq[c], bk, a, 0, 0, 0);
      }
      sa[t] = a;
    }
    __builtin_amdgcn_s_setprio(0);

    // online softmax per row (rows = myq + r); sum comes from the PV MFMA
    float alpha[4];
#pragma unroll
    for (int r = 0; r < 4; ++r) {
      const int row = myq + r;
      float s[4];
#pragma unroll
      for (int t = 0; t < 4; ++t) {
        float v = sa[t][r] * scale;
        if (dg) v = (kv0 + t * 16 + lr <= row) ? v : NEG_BIG;
        s[t] = v;
      }
      float mx = fmaxf(fmaxf(s[0], s[1]), fmaxf(s[2], s[3]));
#pragma unroll
      for (int off = 8; off >= 1; off >>= 1) mx = fmaxf(mx, __shfl_xor(mx, off));
      float mn = fmaxf(m_run[r], mx);
      alpha[r] = __expf(m_run[r] - mn);
      m_run[r] = mn;
      const int q  = quad * 4 + r;
      const int sw = (q & 7) << 3;
      const int base = wave * 1152 + q * 72;
#pragma unroll
      for (int t = 0; t < 4; ++t)
        Ps[base + ((t * 16 + lr) ^ sw)] = f2bf(__expf(s[t] - mn));
    }
#pragma unroll
    for (int nt = 0; nt < 9; ++nt)
#pragma unroll
      for (int r = 0; r < 4; ++r) accO[nt][r] *= alpha[r];

    // O += P V : 2 k-steps of 32 kv, 9 d-tiles (tile 8 = denominator)
    __builtin_amdgcn_s_setprio(1);
#pragma unroll
    for (int kt2 = 0; kt2 < 2; ++kt2) {
      bf16x8 pf = *(const bf16x8*)&Ps[wave * 1152 + lr * 72 +
                                      ((kt2 * 32 + quad * 8) ^ ((lr & 7) << 3))];
#pragma unroll
      for (int nt = 0; nt < 9; ++nt) {
        const int d = nt * 16 + lr;
        bf16x8 vf = *(const bf16x8*)&Vs[d * 72 +
                                        ((kt2 * 32 + quad * 8) ^ (((d >> 3) & 7) << 3))];
        accO[nt] = __builtin_amdgcn_mfma_f32_16x16x32_bf16(pf, vf, accO[nt], 0, 0, 0);
      }
    }
    __builtin_amdgcn_s_setprio(0);
  }

  // l for row q lives in lane lr==0 of the same quad (d=128 column)
  float rl[4];
#pragma unroll
  for (int r = 0; r < 4; ++r) {
    float l = __shfl(accO[8][r], lane & 48);
    rl[r] = 1.0f / l;
  }
#pragma unroll
  for (int nt = 0; nt < 8; ++nt)
#pragma unroll
    for (int r = 0; r < 4; ++r) {
      size_t q = (size_t)(wbase + quad * 4 + r);
      O[((size_t)b * S_LEN + q) * DMODEL + (size_t)h * HD + nt * 16 + lr] =
          f2bf(accO[nt][r] * rl[r]);
    }
}

extern "C" void kernel_launch(void* const* d_in, const int* in_sizes, int n_in,
                              void* d_out, int out_size, void* d_ws, size_t ws_size,
                              hipStream_t stream)
{
  const float* x  = (const float*)d_in[0];
  const float* cp = (const float*)d_in[1];
  const float* sp = (const float*)d_in[2];
  const float* Wq = (const float*)d_in[3];
  const float* Wk = (const float*)d_in[4];
  const float* Wv = (const float*)d_in[5];
  const float* Wo = (const float*)d_in[6];

  // ws layout (bf16 elems): Wt 25,165,824 | Yq 16,777,216 | Yk 4,194,304 |
  // Yv 4,194,304. Vt (4M elems) reuses the START of Wt (weights dead after
  // gemm_qkv; attn finishes before transpose_w(Wo) overwrites Wt).
  // xb (bf16 copy of x) lives in d_out — dead before gemm_o writes output.
  u16* Wt  = (u16*)d_ws;
  u16* Yq  = Wt + (size_t)25165824;
  u16* Yk  = Yq + (size_t)16777216;
  u16* Yv  = Yk + (size_t)4194304;
  u16* att = Yq;                       // attn output aliases Q
  u16* WoT = Wt;                       // dead after QKV GEMM
  u16* Vt  = Wt;                       // transposed V, dead before WoT write
  u16* xb  = (u16*)d_out;              // scratch in output buffer

  transpose_w<<<dim3(64, 64), 256, 0, stream>>>(Wq, Wt,                    4096);
  transpose_w<<<dim3(64, 16), 256, 0, stream>>>(Wk, Wt + (size_t)4096*4096, 1024);
  transpose_w<<<dim3(64, 16), 256, 0, stream>>>(Wv, Wt + (size_t)5120*4096, 1024);
  convert_x<<<8192, 256, 0, stream>>>(x, xb);
  gemm_qkv<<<dim3(48, 32), 256, 0, stream>>>(xb, Wt, cp, sp, Yq, Yk, Yv);
  transpose_v<<<dim3(32, 2, 16), 256, 0, stream>>>(Yv, Vt);
  attn_kernel<<<dim3(16, 32, 2), 512, 0, stream>>>(Yq, Yk, Vt, att);
  transpose_w<<<dim3(64, 64), 256, 0, stream>>>(Wo, WoT, 4096);
  gemm_o<<<dim3(32, 32), 256, 0, stream>>>(att, WoT, (float*)d_out);
}